// Round 3
// baseline (464.157 us; speedup 1.0000x reference)
//
#include <hip/hip_runtime.h>

typedef __bf16 bf16x8 __attribute__((ext_vector_type(8)));
typedef float  f32x4  __attribute__((ext_vector_type(4)));

#define LOG2E 1.4426950408889634f

__device__ __forceinline__ float fexp(float x){ return __builtin_amdgcn_exp2f(x * LOG2E); }
__device__ __forceinline__ float sigm(float x){ return __builtin_amdgcn_rcpf(1.0f + fexp(-x)); }
__device__ __forceinline__ float ftanh(float x){
  float ax = fabsf(x);
  float e  = fexp(-2.0f * ax);
  float t  = (1.0f - e) * __builtin_amdgcn_rcpf(1.0f + e);
  return copysignf(t, x);
}
__device__ __forceinline__ f32x4 MFMA(bf16x8 a, bf16x8 b, f32x4 c){
  return __builtin_amdgcn_mfma_f32_16x16x32_bf16(a, b, c, 0, 0, 0);
}

// B=2048, T=128, D=32, H=256, S=39, PM=12
// 128 wg x 1024 threads (16 waves). Each wave owns ONE n-tile (16 hidden cols)
// across all 3 gates -> per-wave weight regs: 6 h-K-tiles*3*4=72 + x-tile 12 = 84,
// total demand ~125 <= the 128-arch-VGPR cap the backend enforces (R1/R2 showed
// it will NOT exceed 128 arch regs regardless of waves_per_eu hints -> 8-wave
// design spilled 650B/thread). h-K-tiles 6,7 weights live in LDS instead.
__global__ void
__attribute__((amdgpu_flat_work_group_size(1024,1024), amdgpu_waves_per_eu(4,4)))
ealstm_kernel(
    const float* __restrict__ x,      const float* __restrict__ latlons,
    const float* __restrict__ yearly, const float* __restrict__ pm,
    const float* __restrict__ Wf_i, const float* __restrict__ Wf_h, const float* __restrict__ bf_h,
    const float* __restrict__ Wu,   const float* __restrict__ bu,
    const float* __restrict__ Wg_i, const float* __restrict__ Wg_h, const float* __restrict__ bg_h,
    const float* __restrict__ Wo_i, const float* __restrict__ Wo_h, const float* __restrict__ bo_h,
    const float* __restrict__ Wd0,  const float* __restrict__ bd0,
    const float* __restrict__ Wd1,  const float* __restrict__ bd1,
    float* __restrict__ out)
{
  // LDS: 16896 + 2048 + 98304 + 4096 = 121344 B  (1 block/CU)
  __shared__ __align__(16) __bf16 hbuf[2][16*264];   // h state, double buffered, stride 264 (+8 pad)
  __shared__ __align__(16) __bf16 xbuf[2][16*32];    // x_t tile, double buffered
  __shared__ __align__(16) __bf16 wlds[96*512];      // B-frags for h K-tiles 6,7: frag(s*48+g*16+nt)
  __shared__ __align__(16) float  xs[16*64];         // [latlons|yearly|0pad] padded to K=64

  const int tid  = threadIdx.x;
  const int w    = tid >> 6;      // wave 0..15 == n-tile index
  const int lane = tid & 63;
  const int q    = lane >> 4;     // quad 0..3
  const int l    = lane & 15;
  const int wgb  = blockIdx.x * 16;
  const int colc = w*16 + l;      // this thread's hidden column

  const float* Wh[3] = {Wf_h, Wg_h, Wo_h};
  const float* Wi[3] = {Wf_i, Wg_i, Wo_i};
  const float* bH[3] = {bf_h, bg_h, bo_h};

  // ---------------- init: LDS fills ----------------
  { // xs: exactly 1024 elems
    int m = tid >> 6, k = tid & 63;
    int b = wgb + m;
    float v = 0.0f;
    if(k < 2) v = latlons[b*2 + k];
    else if(k < 39) v = yearly[b*37 + (k-2)];
    xs[tid] = v;
  }
  for(int idx = tid; idx < 16*264; idx += 1024) hbuf[0][idx] = (__bf16)0.0f;
  if(tid < 512){
    int m = tid >> 5, k = tid & 31;
    xbuf[0][tid] = (__bf16)x[(size_t)(wgb + m)*4096 + k];   // t = 0
  }
  // wlds fill: 96 frags x 64 lane-chunks of 8 bf16
  for(int grp = tid; grp < 96*64; grp += 1024){
    int frag = grp >> 6;
    int ln   = grp & 63;
    int s  = (frag >= 48) ? 1 : 0;
    int f2 = frag - s*48;
    int g  = f2 >> 4;
    int nt = f2 & 15;
    int q2 = ln >> 4, l2 = ln & 15;
    int cc2 = nt*16 + l2;
    const float* wsrc = (g == 0) ? Wf_h : (g == 1) ? Wg_h : Wo_h;
    const float* p = wsrc + cc2*256 + (6+s)*32 + q2*8;
    bf16x8 v;
    #pragma unroll
    for(int j=0;j<8;j++) v[j] = (__bf16)p[j];
    *(bf16x8*)&wlds[frag*512 + ln*8] = v;
  }

  // ---------------- init: register-resident weights ----------------
  bf16x8 wreg[3][6];   // h K-tiles 0..5
  bf16x8 wx[3];        // x K-tile
  #pragma unroll
  for(int g=0; g<3; g++){
    #pragma unroll
    for(int kt=0; kt<6; kt++){
      const float* p = Wh[g] + colc*256 + kt*32 + q*8;
      f32x4 v0 = *(const f32x4*)p;
      f32x4 v1 = *(const f32x4*)(p + 4);
      bf16x8 v;
      v[0]=(__bf16)v0[0]; v[1]=(__bf16)v0[1]; v[2]=(__bf16)v0[2]; v[3]=(__bf16)v0[3];
      v[4]=(__bf16)v1[0]; v[5]=(__bf16)v1[1]; v[6]=(__bf16)v1[2]; v[7]=(__bf16)v1[3];
      wreg[g][kt] = v;
    }
    const float* p = Wi[g] + colc*32 + q*8;
    f32x4 v0 = *(const f32x4*)p;
    f32x4 v1 = *(const f32x4*)(p + 4);
    bf16x8 v;
    v[0]=(__bf16)v0[0]; v[1]=(__bf16)v0[1]; v[2]=(__bf16)v0[2]; v[3]=(__bf16)v0[3];
    v[4]=(__bf16)v1[0]; v[5]=(__bf16)v1[1]; v[6]=(__bf16)v1[2]; v[7]=(__bf16)v1[3];
    wx[g] = v;
  }
  const float b0v = bH[0][colc];
  const float b1v = bH[1][colc];
  const float b2v = bH[2][colc];
  const float buv = bu[colc];

  __syncthreads();

  // ---------------- i_gate = sigmoid(x_s @ Wu^T + bu) via MFMA ----------------
  f32x4 ig;
  {
    f32x4 iga = {buv, buv, buv, buv};
    #pragma unroll
    for(int kt=0; kt<2; kt++){
      bf16x8 a, b;
      const float* xr = &xs[l*64 + kt*32 + q*8];
      #pragma unroll
      for(int j=0;j<8;j++) a[j] = (__bf16)xr[j];
      #pragma unroll
      for(int j=0;j<8;j++){
        int k = kt*32 + q*8 + j;
        b[j] = (__bf16)((k < 39) ? Wu[colc*39 + k] : 0.0f);
      }
      iga = MFMA(a, b, iga);
    }
    #pragma unroll
    for(int i=0;i<4;i++) ig[i] = sigm(iga[i]);
  }

  f32x4 cst = {0.f, 0.f, 0.f, 0.f};

  // ---------------- recurrence: 128 steps, 1 barrier/step ----------------
#define LSTM_STEP(T_, CUR_)                                                     \
  {                                                                             \
    const int t = (T_);                                                         \
    f32x4 acc0 = {b0v,b0v,b0v,b0v};                                             \
    f32x4 acc1 = {b1v,b1v,b1v,b1v};                                             \
    f32x4 acc2 = {b2v,b2v,b2v,b2v};                                             \
    const __bf16* hb = hbuf[CUR_];                                              \
    _Pragma("unroll")                                                           \
    for(int kt=0; kt<6; kt++){                                                  \
      bf16x8 a = *(const bf16x8*)&hb[l*264 + kt*32 + q*8];                      \
      acc0 = MFMA(a, wreg[0][kt], acc0);                                        \
      acc1 = MFMA(a, wreg[1][kt], acc1);                                        \
      acc2 = MFMA(a, wreg[2][kt], acc2);                                        \
    }                                                                           \
    _Pragma("unroll")                                                           \
    for(int s=0; s<2; s++){                                                     \
      bf16x8 a = *(const bf16x8*)&hb[l*264 + (6+s)*32 + q*8];                   \
      acc0 = MFMA(a, *(const bf16x8*)&wlds[(s*48 +  0 + w)*512 + lane*8], acc0);\
      acc1 = MFMA(a, *(const bf16x8*)&wlds[(s*48 + 16 + w)*512 + lane*8], acc1);\
      acc2 = MFMA(a, *(const bf16x8*)&wlds[(s*48 + 32 + w)*512 + lane*8], acc2);\
    }                                                                           \
    {                                                                           \
      bf16x8 a = *(const bf16x8*)&xbuf[CUR_][l*32 + q*8];                       \
      acc0 = MFMA(a, wx[0], acc0);                                              \
      acc1 = MFMA(a, wx[1], acc1);                                              \
      acc2 = MFMA(a, wx[2], acc2);                                              \
    }                                                                           \
    if(w == 0 && t < 127){                                                      \
      int row = lane >> 2, c0 = (lane & 3) * 8;                                 \
      const float* xp = x + (size_t)(wgb + row)*4096 + (t+1)*32 + c0;           \
      f32x4 v0 = *(const f32x4*)xp;                                             \
      f32x4 v1 = *(const f32x4*)(xp + 4);                                       \
      bf16x8 v;                                                                 \
      v[0]=(__bf16)v0[0]; v[1]=(__bf16)v0[1]; v[2]=(__bf16)v0[2]; v[3]=(__bf16)v0[3]; \
      v[4]=(__bf16)v1[0]; v[5]=(__bf16)v1[1]; v[6]=(__bf16)v1[2]; v[7]=(__bf16)v1[3]; \
      *(bf16x8*)&xbuf[(CUR_) ^ 1][row*32 + c0] = v;                             \
    }                                                                           \
    _Pragma("unroll")                                                           \
    for(int i=0;i<4;i++){                                                       \
      float fv = sigm (acc0[i]);                                                \
      float gv = ftanh(acc1[i]);                                                \
      float ov = sigm (acc2[i]);                                                \
      float cc = fv * cst[i] + ig[i] * gv;                                      \
      cst[i] = cc;                                                              \
      hbuf[(CUR_) ^ 1][(q*4 + i)*264 + colc] = (__bf16)(ov * ftanh(cc));        \
    }                                                                           \
    __syncthreads();                                                            \
  }

  #pragma unroll 1
  for(int tt = 0; tt < 64; tt++){
    LSTM_STEP(2*tt,     0)
    LSTM_STEP(2*tt + 1, 1)
  }
#undef LSTM_STEP

  // ---------------- head: z1 = [h_last, pm] @ Wd0^T + bd0 ; out = z1 @ Wd1^T + bd1 ----------------
  // h_last is in hbuf[0] (t=127 wrote buffer 0)
  f32x4 hd = {0.f, 0.f, 0.f, 0.f};
  #pragma unroll
  for(int kt=0; kt<8; kt++){
    bf16x8 a = *(const bf16x8*)&hbuf[0][l*264 + kt*32 + q*8];
    const float* p = Wd0 + colc*268 + kt*32 + q*8;
    bf16x8 b;
    #pragma unroll
    for(int j=0;j<8;j++) b[j] = (__bf16)p[j];
    hd = MFMA(a, b, hd);
  }
  { // K-tile 8: pm part (k = 256..267), rest zero
    bf16x8 a, b;
    #pragma unroll
    for(int j=0;j<8;j++){
      int k2 = q*8 + j;
      a[j] = (__bf16)((k2 < 12) ? pm[(size_t)(wgb + l)*12 + k2] : 0.0f);
      b[j] = (__bf16)((k2 < 12) ? Wd0[colc*268 + 256 + k2] : 0.0f);
    }
    hd = MFMA(a, b, hd);
  }
  // z1 to LDS (reuse wlds; its last reads were before the loop-final barrier)
  float* z1 = (float*)wlds;
  {
    float bb = bd0[colc];
    #pragma unroll
    for(int i=0;i<4;i++) z1[(q*4 + i)*264 + colc] = hd[i] + bb;
  }
  __syncthreads();
  if(tid < 512){
    int row = tid >> 5, seg = tid & 31;   // 16 rows x 32 partial-segments
    const float* zr = &z1[row*264 + seg*8];
    const float* wr = Wd1 + seg*8;
    float s = 0.0f;
    #pragma unroll
    for(int j=0;j<8;j++) s += zr[j] * wr[j];
    s += __shfl_xor(s, 1);
    s += __shfl_xor(s, 2);
    s += __shfl_xor(s, 4);
    s += __shfl_xor(s, 8);
    s += __shfl_xor(s, 16);
    if(seg == 0) out[wgb + row] = s + bd1[0];
  }
}

extern "C" void kernel_launch(void* const* d_in, const int* in_sizes, int n_in,
                              void* d_out, int out_size, void* d_ws, size_t ws_size,
                              hipStream_t stream) {
  const float* x       = (const float*)d_in[0];
  const float* latlons = (const float*)d_in[1];
  const float* yearly  = (const float*)d_in[2];
  const float* pm      = (const float*)d_in[3];
  const float* Wf_i    = (const float*)d_in[4];
  const float* Wf_h    = (const float*)d_in[5];
  const float* bf_h    = (const float*)d_in[6];
  const float* Wu      = (const float*)d_in[7];
  const float* bu      = (const float*)d_in[8];
  const float* Wg_i    = (const float*)d_in[9];
  const float* Wg_h    = (const float*)d_in[10];
  const float* bg_h    = (const float*)d_in[11];
  const float* Wo_i    = (const float*)d_in[12];
  const float* Wo_h    = (const float*)d_in[13];
  const float* bo_h    = (const float*)d_in[14];
  const float* Wd0     = (const float*)d_in[15];
  const float* bd0     = (const float*)d_in[16];
  const float* Wd1     = (const float*)d_in[17];
  const float* bd1     = (const float*)d_in[18];

  ealstm_kernel<<<dim3(128), dim3(1024), 0, stream>>>(
      x, latlons, yearly, pm,
      Wf_i, Wf_h, bf_h, Wu, bu,
      Wg_i, Wg_h, bg_h, Wo_i, Wo_h, bo_h,
      Wd0, bd0, Wd1, bd1,
      (float*)d_out);
}